// Round 3
// baseline (356.379 us; speedup 1.0000x reference)
//
#include <hip/hip_runtime.h>

// Batched Viterbi decode: B=1024, S=512, T=64.
// R6: forward restructured to kill LDS-pipe contention (the R5 bottleneck:
// 16 ds_read_b128/step/wave x 4 waves/CU ~= 768 LDS cyc/CU-step vs ~280 VALU
// cyc/SIMD-step -> VALUBusy 51%). New layout: lane L=(gn=L>>3, gp=L&7)
// computes partials for n in {8gn..8gn+7} over p in {8gp..8gp+7} (T as 64
// regs, v_pk_add_f32 packed adds, max3 trees), then 3 DPP max rounds
// (quad_perm ^1, ^2, row_half_mirror -- pure VALU, no LDS) all-reduce each
// gn-group, 7 cndmask select -> fv[L] at lane L. LDS/step: 17 ops -> 3.
// Reduction order is bit-safe for the equality backtrace: fmax returns one
// operand bitwise; ballot compares by VALUE so first-match == jnp argmax.
// Backtrace identical to verified R5. R4 fallback if ws too small.

typedef float v2f __attribute__((ext_vector_type(2)));

#define B_ 1024
#define S_ 512
#define T_ 64
#define NEGV -10000.0f

#define DPP_XOR1 0xB1        // quad_perm(1,0,3,2)
#define DPP_XOR2 0x4E        // quad_perm(2,3,0,1)
#define DPP_HMIRR 0x141      // row_half_mirror (xor7 within 8 lanes)

template <int CTRL>
__device__ __forceinline__ float dppmax(float x) {
    const int y = __builtin_amdgcn_update_dpp(0, __float_as_int(x), CTRL, 0xf, 0xf, true);
    return fmaxf(x, __int_as_float(y));
}

// ---------------- R6 fast path ----------------
__global__ __launch_bounds__(64, 1) void viterbi_fwd_bt(
    const float* __restrict__ feats,   // [B, S, T]
    const float* __restrict__ trans,   // [T, T]
    float* __restrict__ out,           // [B + B*S]
    float* __restrict__ vv)            // workspace [B, S, T]: pre-feat max per step
{
    __shared__ float T_lds[T_ * T_];              // 16 KB transitions copy (row-major)
    __shared__ __align__(16) float fvbuf[2][T_];  // parity-double-buffered fv

    const int b = blockIdx.x;
    const int lane = threadIdx.x;
    const int gn = lane >> 3;          // n-group (owns next-tags 8gn..8gn+7)
    const int gp = lane & 7;           // p-chunk (owns prev-tags 8gp..8gp+7)

    // stage transitions into LDS for backtrace row reads (coalesced float4)
    {
        const float4* src = reinterpret_cast<const float4*>(trans);
        float4* dst = reinterpret_cast<float4*>(T_lds);
#pragma unroll
        for (int i = 0; i < 16; ++i) dst[i * 64 + lane] = src[i * 64 + lane];
    }

    // T8[i][*]: row n=8gn+i, cols p=8gp..8gp+7, packed as 4x v2f (64 VGPRs)
    v2f T8[8][4];
#pragma unroll
    for (int i = 0; i < 8; ++i) {
        const float* r = trans + (8 * gn + i) * T_ + 8 * gp;
        const float4 u0 = *reinterpret_cast<const float4*>(r);
        const float4 u1 = *reinterpret_cast<const float4*>(r + 4);
        T8[i][0] = v2f{u0.x, u0.y}; T8[i][1] = v2f{u0.z, u0.w};
        T8[i][2] = v2f{u1.x, u1.y}; T8[i][3] = v2f{u1.z, u1.w};
    }
    const float tend = trans[(T_ - 1) * T_ + lane];   // transitions[END][lane]

    // select masks (hoisted once)
    const bool s0 = (lane & 1) != 0;
    const bool s1 = (lane & 2) != 0;
    const bool s2 = (lane & 4) != 0;

    float fv = (lane == T_ - 2) ? 0.0f : NEGV;        // START = T-2
    fvbuf[0][lane] = fv;

    const float* fb = feats + (size_t)b * S_ * T_ + lane;
    float* vw = vv + (size_t)b * S_ * T_ + lane;

    // feat prefetch ring: 4 steps ahead
    float fc[4], fn[4];
#pragma unroll
    for (int k = 0; k < 4; ++k) fc[k] = fb[(size_t)k * T_];

#pragma unroll 1
    for (int s4 = 0; s4 < S_ / 4; ++s4) {
#pragma unroll
        for (int k = 0; k < 4; ++k) {
            int sp = 4 * s4 + 4 + k;
            sp = (sp < S_) ? sp : (S_ - 1);
            fn[k] = fb[(size_t)sp * T_];
        }
#pragma unroll
        for (int u = 0; u < 4; ++u) {
            const int s = 4 * s4 + u;
            const int rs = s & 1;

            // read my 8 fv values (2x ds_read_b128, 8-way broadcast, <=2-way alias)
            const float4 a0 = *reinterpret_cast<const float4*>(&fvbuf[rs][8 * gp]);
            const float4 a1 = *reinterpret_cast<const float4*>(&fvbuf[rs][8 * gp + 4]);
            const v2f f0 = v2f{a0.x, a0.y}, f1 = v2f{a0.z, a0.w};
            const v2f f2 = v2f{a1.x, a1.y}, f3 = v2f{a1.z, a1.w};

            // partial max over my 8 p's for each of my 8 n's (pk_add + max3 tree)
            float m[8];
#pragma unroll
            for (int i = 0; i < 8; ++i) {
                const v2f c0 = f0 + T8[i][0];
                const v2f c1 = f1 + T8[i][1];
                const v2f c2 = f2 + T8[i][2];
                const v2f c3 = f3 + T8[i][3];
                const float x = fmaxf(fmaxf(c0.x, c0.y), c1.x);   // -> v_max3
                const float y = fmaxf(fmaxf(c1.y, c2.x), c2.y);   // -> v_max3
                const float z = fmaxf(c3.x, c3.y);
                m[i] = fmaxf(fmaxf(x, y), z);                     // -> v_max3
            }

            // all-reduce max across the 8 lanes of this gn-group (pure VALU DPP)
#pragma unroll
            for (int i = 0; i < 8; ++i) m[i] = dppmax<DPP_XOR1>(m[i]);
#pragma unroll
            for (int i = 0; i < 8; ++i) m[i] = dppmax<DPP_XOR2>(m[i]);
#pragma unroll
            for (int i = 0; i < 8; ++i) m[i] = dppmax<DPP_HMIRR>(m[i]);

            // select own tag's value: index gp = lane&7 (7 cndmask)
            const float x0 = s0 ? m[1] : m[0];
            const float x1 = s0 ? m[3] : m[2];
            const float x2 = s0 ? m[5] : m[4];
            const float x3 = s0 ? m[7] : m[6];
            const float y0 = s1 ? x1 : x0;
            const float y1 = s1 ? x3 : x2;
            const float maxv = s2 ? y1 : y0;

            vw[(size_t)s * T_] = maxv;        // store pre-feat viterbivars (exact)
            fv = maxv + fc[u];
            fvbuf[rs ^ 1][lane] = fv;
        }
#pragma unroll
        for (int k = 0; k < 4; ++k) fc[k] = fn[k];
    }

    // terminal: max/argmax over tags (butterfly, first-index ties)
    float v = fv + tend;
    int i = lane;
#pragma unroll
    for (int off = 1; off < 64; off <<= 1) {
        const float vo = __shfl_xor(v, off);
        const int io = __shfl_xor(i, off);
        const bool take = (vo > v) || ((vo == v) && (io < i));
        v = take ? vo : v;
        i = take ? io : i;
    }
    int ncur = __builtin_amdgcn_readfirstlane(i);
    if (lane == 0) out[b] = v;

    // ---- backtrace: equality search, 1 ballot per step (verified R5) ----
    asm volatile("s_waitcnt vmcnt(0)" ::: "memory");  // vv stores visible to our loads

    float A = vw[(size_t)(S_ - 1) * T_];              // vv_511 vector (lane p holds [p])
    float vvR[8], ffR[8];
#pragma unroll
    for (int k = 0; k < 8; ++k) {
        const int s = (S_ - 1) - k;
        vvR[k] = vw[(size_t)(s - 1) * T_];
        ffR[k] = fb[(size_t)(s - 1) * T_];
    }

    float emitv = 0.0f;
    float* outp = out + B_ + (size_t)b * S_;

#pragma unroll 1
    for (int c = 7; c >= 0; --c) {
#pragma unroll 1
        for (int g = 7; g >= 0; --g) {
            const int base = 64 * c + 8 * g;
#pragma unroll
            for (int kk = 0; kk < 8; ++kk) {
                const int s = base + 7 - kk;
                emitv = (lane == (s & 63)) ? (float)ncur : emitv;
                if (s > 0) {
                    const float target = __int_as_float(
                        __builtin_amdgcn_readlane(__float_as_int(A), ncur));
                    const float trow = T_lds[(ncur << 6) + lane];
                    const float cand = (vvR[kk] + ffR[kk]) + trow;
                    const unsigned long long msk = __ballot(cand == target);
                    ncur = ((int)__builtin_ctzll(msk)) & 63;
                    A = vvR[kk];
                    const int sp = (s >= 9) ? (s - 9) : 0;
                    vvR[kk] = vw[(size_t)sp * T_];
                    ffR[kk] = fb[(size_t)sp * T_];
                }
            }
        }
        outp[64 * c + lane] = emitv;
    }
}

// ---------------- R4 fallback (verified; used when workspace too small) ----------------
__global__ __launch_bounds__(64, 1) void viterbi_kernel(
    const float* __restrict__ feats,
    const float* __restrict__ trans,
    float* __restrict__ out)
{
    __shared__ unsigned int bp[S_ / 4][T_];
    __shared__ __align__(16) float fvbuf[2][T_];

    const int b = blockIdx.x;
    const int lane = threadIdx.x;

    float t[T_];
#pragma unroll
    for (int p = 0; p < T_; p += 4) {
        const float4 v = *reinterpret_cast<const float4*>(trans + lane * T_ + p);
        t[p] = v.x; t[p + 1] = v.y; t[p + 2] = v.z; t[p + 3] = v.w;
    }
    const float tend = trans[(T_ - 1) * T_ + lane];

    float fv = (lane == T_ - 2) ? 0.0f : NEGV;
    fvbuf[0][lane] = fv;

    const float* fb = feats + (size_t)b * S_ * T_ + lane;

    float fc[4], fn[4];
#pragma unroll
    for (int k = 0; k < 4; ++k) fc[k] = fb[(size_t)k * T_];

#pragma unroll 1
    for (int s4 = 0; s4 < S_ / 4; ++s4) {
#pragma unroll
        for (int k = 0; k < 4; ++k) {
            int sp = 4 * s4 + 4 + k;
            sp = (sp < S_) ? sp : (S_ - 1);
            fn[k] = fb[(size_t)sp * T_];
        }

        unsigned int pack = 0;
#pragma unroll
        for (int u = 0; u < 4; ++u) {
            const int s = 4 * s4 + u;
            const int rs = s & 1;

            float fvl[T_];
#pragma unroll
            for (int j = 0; j < 16; ++j) {
                const float4 v = *reinterpret_cast<const float4*>(&fvbuf[rs][4 * j]);
                fvl[4 * j] = v.x; fvl[4 * j + 1] = v.y;
                fvl[4 * j + 2] = v.z; fvl[4 * j + 3] = v.w;
            }

            float bv[4]; int bi[4];
#pragma unroll
            for (int g = 0; g < 4; ++g) {
                float bestv = fvl[16 * g] + t[16 * g];
                int besti = 16 * g;
#pragma unroll
                for (int q = 1; q < 16; ++q) {
                    const int p = 16 * g + q;
                    const float c = fvl[p] + t[p];
                    const bool gt = c > bestv;
                    besti = gt ? p : besti;
                    bestv = gt ? c : bestv;
                }
                bv[g] = bestv; bi[g] = besti;
            }
            float BV = bv[0]; int BI = bi[0];
#pragma unroll
            for (int g = 1; g < 4; ++g) {
                const bool gt = bv[g] > BV;
                BI = gt ? bi[g] : BI;
                BV = gt ? bv[g] : BV;
            }

            fv = BV + fc[u];
            fvbuf[rs ^ 1][lane] = fv;
            pack |= ((unsigned int)BI) << (8 * u);
        }
        bp[s4][lane] = pack;

#pragma unroll
        for (int k = 0; k < 4; ++k) fc[k] = fn[k];
    }

    float v = fv + tend;
    int i = lane;
#pragma unroll
    for (int off = 1; off < 64; off <<= 1) {
        const float vo = __shfl_xor(v, off);
        const int io = __shfl_xor(i, off);
        const bool take = (vo > v) || ((vo == v) && (io < i));
        v = take ? vo : v;
        i = take ? io : i;
    }
    int tcur = __builtin_amdgcn_readfirstlane(i);
    if (lane == 0) out[b] = v;

    float* outp = out + B_ + (size_t)b * S_;
#pragma unroll 1
    for (int c = 7; c >= 0; --c) {
        unsigned int wd[16];
#pragma unroll
        for (int j = 0; j < 16; ++j)
            wd[j] = bp[16 * c + j][lane];

        int emit = 0;
#pragma unroll
        for (int k = 63; k >= 0; --k) {
            emit = (lane == k) ? tcur : emit;
            const int word = __builtin_amdgcn_readlane((int)wd[k >> 2], tcur);
            tcur = (word >> (8 * (k & 3))) & 0xff;
        }
        outp[64 * c + lane] = (float)emit;
    }
}

extern "C" void kernel_launch(void* const* d_in, const int* in_sizes, int n_in,
                              void* d_out, int out_size, void* d_ws, size_t ws_size,
                              hipStream_t stream) {
    const float* feats = (const float*)d_in[0];   // [B*S*T] f32
    const float* trans = (const float*)d_in[1];   // [T*T] f32
    float* out = (float*)d_out;                   // [B + B*S] f32

    const size_t need = (size_t)B_ * S_ * T_ * sizeof(float);  // 128 MiB
    if (d_ws != nullptr && ws_size >= need) {
        viterbi_fwd_bt<<<dim3(B_), dim3(T_), 0, stream>>>(feats, trans, out, (float*)d_ws);
    } else {
        viterbi_kernel<<<dim3(B_), dim3(T_), 0, stream>>>(feats, trans, out);
    }
}